// Round 7
// baseline (2998.377 us; speedup 1.0000x reference)
//
#include <hip/hip_runtime.h>

typedef _Float16 f16_t;
typedef _Float16 f16x8 __attribute__((ext_vector_type(8)));
typedef _Float16 f16x4 __attribute__((ext_vector_type(4)));
typedef _Float16 f16x2 __attribute__((ext_vector_type(2)));
typedef float    f32x4 __attribute__((ext_vector_type(4)));

#define LAYERS 12
#define HDIM   256
#define CDIM   256
#define BROWS  32     // batch rows per block

// packed-weight workspace layout (f16 elements)
#define W0P_OFF 0
#define WCP_OFF 8192
#define WRP_OFF 73728
#define WRP_SZ  65536
#define WFP_OFF 335872
#define LSTRIDE 532480
#define PACK_TOTAL (LAYERS * LSTRIDE)
#define CTX_BYTE ((size_t)PACK_TOTAL * 2)

// ---------------------------------------------------------------------------
// Prepass: mask + cast + pack weights into MFMA B-fragment order.
// B-frag for 16x16x32: element (n = lane&15, k = quad*8+j) of tile (nt,kt)
// stored at ((nt*KT + kt)*64 + lane)*8 + j  -> one 16B load per lane.
// ---------------------------------------------------------------------------
__global__ __launch_bounds__(256) void nsf_pack(
    const float* __restrict__ W0, const float* __restrict__ Wc,
    const float* __restrict__ Wr, const float* __restrict__ Wf,
    f16_t* __restrict__ wp)
{
    int e = blockIdx.x * 256 + threadIdx.x;
    if (e >= PACK_TOTAL) return;
    int l = e / LSTRIDE;
    int r = e - l * LSTRIDE;
    float v = 0.f;
    if (r < WCP_OFF) {                       // W0p: N=256, K=32 (padded from 16), masked m0
        int t = r >> 9, lane = (r >> 3) & 63, j = r & 7;
        int n = t * 16 + (lane & 15);
        int k = (lane >> 4) * 8 + j;
        if (k < 16 && (n % 15 + 1) >= (k + 1))
            v = W0[(l * HDIM + n) * 16 + k];
    } else if (r < WRP_OFF) {                // Wcp: N=256, K=256, no mask
        int q = r - WCP_OFF;
        int t = q >> 9, lane = (q >> 3) & 63, j = q & 7;
        int n = (t >> 3) * 16 + (lane & 15);
        int k = (t & 7) * 32 + (lane >> 4) * 8 + j;
        v = Wc[(l * HDIM + n) * CDIM + k];
    } else if (r < WFP_OFF) {                // Wrp[4]: N=256, K=256, masked mh
        int q = r - WRP_OFF;
        int rr = q >> 16; q &= 65535;
        int t = q >> 9, lane = (q >> 3) & 63, j = q & 7;
        int n = (t >> 3) * 16 + (lane & 15);
        int k = (t & 7) * 32 + (lane >> 4) * 8 + j;
        if ((n % 15) >= (k % 15))
            v = Wr[(((l * 2 + (rr >> 1)) * 2 + (rr & 1)) * HDIM + n) * HDIM + k];
    } else {                                 // Wfp: N=768 (16 feats x 48, padded from 47), masked mf
        int q = r - WFP_OFF;
        int t = q >> 9, lane = (q >> 3) & 63, j = q & 7;
        int np = (t >> 3) * 16 + (lane & 15);
        int k = (t & 7) * 32 + (lane >> 4) * 8 + j;
        int f = np / 48, jj = np % 48;
        if (jj < 47 && (f + 1) > (k % 15 + 1))
            v = Wf[(l * 752 + f * 47 + jj) * HDIM + k];
    }
    wp[e] = (f16_t)v;
}

__global__ __launch_bounds__(256) void nsf_ctx16(
    const float* __restrict__ ctx, f16_t* __restrict__ c16, int n4)
{
    int i = blockIdx.x * 256 + threadIdx.x;
    if (i >= n4) return;
    float4 v = reinterpret_cast<const float4*>(ctx)[i];
    f16x4 o = { (f16_t)v.x, (f16_t)v.y, (f16_t)v.z, (f16_t)v.w };
    reinterpret_cast<f16x4*>(c16)[i] = o;
}

// ---------------------------------------------------------------------------
__device__ __forceinline__ float splus(float x) {
    return (x > 20.f) ? x : log1pf(__expf(x));
}
__device__ __forceinline__ float loF(unsigned u) {
    f16x2 h = __builtin_bit_cast(f16x2, u); return (float)h[0];
}
__device__ __forceinline__ float hiF(unsigned u) {
    f16x2 h = __builtin_bit_cast(f16x2, u); return (float)h[1];
}

// C = A(32x256, LDS) * W^T(256x256, packed global)  accumulated into acc
__device__ __forceinline__ void gemm256(f32x4 (&acc)[2][4],
                                        const f16_t (&A)[BROWS][264],
                                        const f16_t* __restrict__ wb,
                                        int wave, int lane, int quad, int l16)
{
#pragma unroll
    for (int kt = 0; kt < 8; ++kt) {
        f16x8 a[2];
#pragma unroll
        for (int mi = 0; mi < 2; ++mi)
            a[mi] = *reinterpret_cast<const f16x8*>(&A[mi * 16 + l16][kt * 32 + quad * 8]);
#pragma unroll
        for (int ni = 0; ni < 4; ++ni) {
            f16x8 b = *reinterpret_cast<const f16x8*>(wb + ((((wave * 4 + ni) * 8) + kt) * 64 + lane) * 8);
#pragma unroll
            for (int mi = 0; mi < 2; ++mi)
                acc[mi][ni] = __builtin_amdgcn_mfma_f32_16x16x32_f16(a[mi], b, acc[mi][ni], 0, 0, 0);
        }
    }
}

template <bool RELU>
__device__ __forceinline__ void stage_c(const f32x4 (&acc)[2][4], f16_t (&A)[BROWS][264],
                                        int wave, int quad, int l16)
{
#pragma unroll
    for (int mi = 0; mi < 2; ++mi)
#pragma unroll
        for (int ni = 0; ni < 4; ++ni)
#pragma unroll
            for (int rr = 0; rr < 4; ++rr) {
                float v = acc[mi][ni][rr];
                if (RELU) v = fmaxf(v, 0.f);
                A[mi * 16 + quad * 4 + rr][wave * 64 + ni * 16 + l16] = (f16_t)v;
            }
}

// stage relu(h)->act AND raw h (f16) -> thread-private LDS row
__device__ __forceinline__ void stage_relu_and_h(const f32x4 (&acc)[2][4], f16_t (&A)[BROWS][264],
                                                 f16_t* __restrict__ hrow,
                                                 int wave, int quad, int l16)
{
#pragma unroll
    for (int mi = 0; mi < 2; ++mi)
#pragma unroll
        for (int ni = 0; ni < 4; ++ni) {
            f16x4 hv;
#pragma unroll
            for (int rr = 0; rr < 4; ++rr) {
                float v = acc[mi][ni][rr];
                hv[rr] = (f16_t)v;
                A[mi * 16 + quad * 4 + rr][wave * 64 + ni * 16 + l16] = (f16_t)fmaxf(v, 0.f);
            }
            *reinterpret_cast<f16x4*>(hrow + (mi * 4 + ni) * 4) = hv;
        }
}

// ---------------------------------------------------------------------------
// Persistent flow kernel: each block owns 32 batch rows across all 12 layers.
// Key invariant (round-7): at most ONE 32-float accumulator is live at any
// time — h is parked in a thread-private LDS row (f16) across the residual
// GEMMs, so the 64-AGPR partition never overflows into scratch.
// ---------------------------------------------------------------------------
template <bool CTX16>
__global__ __launch_bounds__(256, 4)
void nsf_flow(
    const float* __restrict__ x_in, const float* __restrict__ ctx32,
    const f16_t* __restrict__ ctx16,
    const float* __restrict__ b0, const float* __restrict__ bc,
    const float* __restrict__ br, const float* __restrict__ bfb,
    const f16_t* __restrict__ wp,
    float* __restrict__ out, int B)
{
    __shared__ f16_t act[BROWS][264];                        // 16896 B
    __shared__ __align__(16) unsigned char pool_[256 * 36 * 2]; // 18432 B: xstage U plds U hstore
    __shared__ float xbuf[BROWS][16];                        // 2048 B   (total 37376 B -> 4 blocks/CU)

    f16_t (*xstage)[40] = reinterpret_cast<f16_t(*)[40]>(pool_);
    f16_t (*plds)[194]  = reinterpret_cast<f16_t(*)[194]>(pool_);

    const int tid  = threadIdx.x;
    f16_t* hrow = reinterpret_cast<f16_t*>(pool_) + tid * 36;   // 32 vals + 4 pad
    const int wave = tid >> 6, lane = tid & 63;
    const int quad = lane >> 4, l16 = lane & 15;
    const int row0 = blockIdx.x * BROWS;
    const bool sact = tid < 128;                 // spline-active threads
    const int srow = (tid >> 2) & 31, sfl = tid & 3;

    for (int i = tid; i < BROWS * 16; i += 256)
        xbuf[i >> 4][i & 15] = x_in[(size_t)row0 * 16 + i];

    float ld_acc = 0.f;

#pragma unroll 1
    for (int l = 0; l < LAYERS; ++l) {
        const f16_t* wl = wp + (size_t)l * LSTRIDE;
        __syncthreads();   // prior layer fully consumed act/plds/xbuf

        // pre-read the 4 spline inputs this thread needs (x overwritten in place later)
        float xval_c[4];
        if (sact) {
#pragma unroll
            for (int c = 0; c < 4; ++c) xval_c[c] = xbuf[srow][15 - (c * 4 + sfl)];
        }

        // stage ctx -> act (f16)
        if (CTX16) {
#pragma unroll
            for (int it = 0; it < 4; ++it) {
                int j = it * 256 + tid;          // 1024 chunks of 16B
                int rr = j >> 5, cg = j & 31;
                f16x8 v = *reinterpret_cast<const f16x8*>(ctx16 + (size_t)(row0 + rr) * CDIM + cg * 8);
                *reinterpret_cast<f16x8*>(&act[rr][cg * 8]) = v;
            }
        } else {
            int rr = tid >> 3, cg = tid & 7;
            const float* cptr = ctx32 + (size_t)(row0 + rr) * CDIM + cg * 32;
#pragma unroll
            for (int it = 0; it < 8; ++it) {
                float4 v = *reinterpret_cast<const float4*>(cptr + it * 4);
                f16x4 w4 = { (f16_t)v.x, (f16_t)v.y, (f16_t)v.z, (f16_t)v.w };
                *reinterpret_cast<f16x4*>(&act[rr][cg * 32 + it * 4]) = w4;
            }
        }
        // stage flipped x (zero-padded K 16..31) -> xstage
        for (int i = tid; i < BROWS * 32; i += 256) {
            int rr = i >> 5, c = i & 31;
            float v = (c < 16) ? xbuf[rr][15 - c] : 0.f;
            xstage[rr][c] = (f16_t)v;
        }
        __syncthreads();

        // ---- h = xf @ (W0*m0)^T + ctx @ Wc^T + b0 + bc ----
        f32x4 hacc[2][4];
#pragma unroll
        for (int ni = 0; ni < 4; ++ni) {
            int n = wave * 64 + ni * 16 + l16;
            float bv = b0[l * HDIM + n] + bc[l * HDIM + n];
#pragma unroll
            for (int mi = 0; mi < 2; ++mi) hacc[mi][ni] = (f32x4){bv, bv, bv, bv};
        }
        {
            f16x8 a[2];
#pragma unroll
            for (int mi = 0; mi < 2; ++mi)
                a[mi] = *reinterpret_cast<const f16x8*>(&xstage[mi * 16 + l16][quad * 8]);
#pragma unroll
            for (int ni = 0; ni < 4; ++ni) {
                f16x8 b = *reinterpret_cast<const f16x8*>(wl + W0P_OFF + ((wave * 4 + ni) * 64 + lane) * 8);
#pragma unroll
                for (int mi = 0; mi < 2; ++mi)
                    hacc[mi][ni] = __builtin_amdgcn_mfma_f32_16x16x32_f16(a[mi], b, hacc[mi][ni], 0, 0, 0);
            }
        }
        gemm256(hacc, act, wl + WCP_OFF, wave, lane, quad, l16);

        // ---- 2 residual blocks; h parked in hrow (LDS) so only one acc is live ----
#pragma unroll 1
        for (int blk = 0; blk < 2; ++blk) {
            __syncthreads();
            stage_relu_and_h(hacc, act, hrow, wave, quad, l16);   // hacc dead after
            __syncthreads();
            f32x4 tacc[2][4];
#pragma unroll
            for (int ni = 0; ni < 4; ++ni) {
                int n = wave * 64 + ni * 16 + l16;
                float bv = br[((l * 2 + blk) * 2 + 0) * HDIM + n];
#pragma unroll
                for (int mi = 0; mi < 2; ++mi) tacc[mi][ni] = (f32x4){bv, bv, bv, bv};
            }
            gemm256(tacc, act, wl + WRP_OFF + (size_t)(blk * 2) * WRP_SZ, wave, lane, quad, l16);
            __syncthreads();
            stage_c<true>(tacc, act, wave, quad, l16);            // tacc dead after
            __syncthreads();
            // new h acc = parked h + b2, then accumulate W2 @ relu(t1)
#pragma unroll
            for (int ni = 0; ni < 4; ++ni) {
                int n = wave * 64 + ni * 16 + l16;
                float bv = br[((l * 2 + blk) * 2 + 1) * HDIM + n];
#pragma unroll
                for (int mi = 0; mi < 2; ++mi) {
                    f16x4 h4 = *reinterpret_cast<const f16x4*>(hrow + (mi * 4 + ni) * 4);
                    hacc[mi][ni] = (f32x4){ (float)h4[0] + bv, (float)h4[1] + bv,
                                            (float)h4[2] + bv, (float)h4[3] + bv };
                }
            }
            gemm256(hacc, act, wl + WRP_OFF + (size_t)(blk * 2 + 1) * WRP_SZ, wave, lane, quad, l16);
        }

        // ---- stage final h (no relu) ----
        __syncthreads();
        stage_c<false>(hacc, act, wave, quad, l16);
        __syncthreads();

        // ---- Gf in 4 chunks of 4 features (192 packed cols), fused spline ----
#pragma unroll
        for (int c = 0; c < 4; ++c) {
            f32x4 pacc[2][3];
            int fme = c * 4 + wave;   // feature this wave's 48 columns belong to
#pragma unroll
            for (int ni = 0; ni < 3; ++ni) {
                int jj = ni * 16 + l16;
                float bv = (jj < 47) ? bfb[l * 752 + fme * 47 + jj] : 0.f;
#pragma unroll
                for (int mi = 0; mi < 2; ++mi) pacc[mi][ni] = (f32x4){bv, bv, bv, bv};
            }
#pragma unroll
            for (int kt = 0; kt < 8; ++kt) {
                f16x8 a[2];
#pragma unroll
                for (int mi = 0; mi < 2; ++mi)
                    a[mi] = *reinterpret_cast<const f16x8*>(&act[mi * 16 + l16][kt * 32 + quad * 8]);
#pragma unroll
                for (int ni = 0; ni < 3; ++ni) {
                    int nt = c * 12 + wave * 3 + ni;
                    f16x8 b = *reinterpret_cast<const f16x8*>(wl + WFP_OFF + ((nt * 8 + kt) * 64 + lane) * 8);
#pragma unroll
                    for (int mi = 0; mi < 2; ++mi)
                        pacc[mi][ni] = __builtin_amdgcn_mfma_f32_16x16x32_f16(a[mi], b, pacc[mi][ni], 0, 0, 0);
                }
            }
            __syncthreads();   // previous chunk's spline done with plds (xstage/hstore dead)
#pragma unroll
            for (int mi = 0; mi < 2; ++mi)
#pragma unroll
                for (int ni = 0; ni < 3; ++ni)
#pragma unroll
                    for (int rr = 0; rr < 4; ++rr)
                        plds[mi * 16 + quad * 4 + rr][wave * 48 + ni * 16 + l16] = (f16_t)pacc[mi][ni][rr];
            __syncthreads();

            // ---- RQ spline: 3-pass LDS-resident (low register pressure).
            // pp = 24 dwords: uw pairs [0..8), uh pairs [8..16), ud pairs [16..24)
            if (sact) {
                int f = c * 4 + sfl;
                float xval = xval_c[c];
                const unsigned* pp = reinterpret_cast<const unsigned*>(&plds[srow][sfl * 48]);

                // pass A: maxes
                float mw = -1e30f, mh2 = -1e30f;
#pragma unroll
                for (int j = 0; j < 8; ++j) {
                    unsigned w2 = pp[j], h2 = pp[8 + j];
                    mw  = fmaxf(mw,  fmaxf(loF(w2), hiF(w2)) * 0.0625f);
                    mh2 = fmaxf(mh2, fmaxf(loF(h2), hiF(h2)) * 0.0625f);
                }
                // pass B: exp-sums
                float sw = 0.f, sh = 0.f;
#pragma unroll
                for (int j = 0; j < 8; ++j) {
                    unsigned w2 = pp[j], h2 = pp[8 + j];
                    sw += __expf(fmaf(loF(w2), 0.0625f, -mw)) + __expf(fmaf(hiF(w2), 0.0625f, -mw));
                    sh += __expf(fmaf(loF(h2), 0.0625f, -mh2)) + __expf(fmaf(hiF(h2), 0.0625f, -mh2));
                }
                float rw = 0.984f / sw, rh = 0.984f / sh;
                float xc = fminf(fmaxf(xval, -3.f), 3.f);
                // pass C: cumsum scan + running bin select
                float cumw = 0.f, cumh = 0.f, dprev = 1.f;
                float icw = -3.f, iwv = 1.f, ich = -3.f, ihv = 1.f, dk = 1.f, dk1 = 1.f;
#pragma unroll
                for (int jp = 0; jp < 8; ++jp) {
                    unsigned w2 = pp[jp], h2 = pp[8 + jp], d2 = pp[16 + jp];
#pragma unroll
                    for (int sub = 0; sub < 2; ++sub) {
                        int j = jp * 2 + sub;
                        float uwj = (sub ? hiF(w2) : loF(w2)) * 0.0625f;
                        float uhj = (sub ? hiF(h2) : loF(h2)) * 0.0625f;
                        float udj = sub ? hiF(d2) : loF(d2);
                        float wj = fmaf(rw, __expf(uwj - mw), 0.001f);
                        float hj = fmaf(rh, __expf(uhj - mh2), 0.001f);
                        float cwn = cumw + wj, chn = cumh + hj;
                        float left  = (j == 0)  ? -3.f : fmaf(6.f, cumw, -3.f);
                        float right = (j == 15) ?  3.f : fmaf(6.f, cwn, -3.f);
                        float hl    = (j == 0)  ? -3.f : fmaf(6.f, cumh, -3.f);
                        float hr    = (j == 15) ?  3.f : fmaf(6.f, chn, -3.f);
                        float dn    = (j == 15) ? 1.f : (0.001f + splus(udj));
                        if (xc >= left) {
                            icw = left; iwv = right - left;
                            ich = hl;   ihv = hr - hl;
                            dk = dprev; dk1 = dn;
                        }
                        cumw = cwn; cumh = chn; dprev = dn;
                    }
                }
                float delta = ihv / iwv;
                float th = (xc - icw) / iwv;
                float omth = 1.f - th;
                float t1m = th * omth;
                float den = delta + (dk + dk1 - 2.f * delta) * t1m;
                float y = ich + ihv * (delta * th * th + dk * t1m) / den;
                float dnum = delta * delta * (dk1 * th * th + 2.f * delta * t1m + dk * omth * omth);
                float ldv = __logf(dnum) - 2.f * __logf(den);
                bool inside = (xval >= -3.f) && (xval <= 3.f);
                xbuf[srow][f] = inside ? y : xval;
                ld_acc += inside ? ldv : 0.f;
            }
        }
    }

    __syncthreads();
    for (int i = tid; i < BROWS * 16; i += 256)
        out[(size_t)row0 * 16 + i] = xbuf[i >> 4][i & 15];
    float v = ld_acc;
    v += __shfl_xor(v, 1);
    v += __shfl_xor(v, 2);
    if (sact && (lane & 3) == 0)
        out[(size_t)B * 16 + row0 + srow] = v;
}

// ---------------------------------------------------------------------------
extern "C" void kernel_launch(void* const* d_in, const int* in_sizes, int n_in,
                              void* d_out, int out_size, void* d_ws, size_t ws_size,
                              hipStream_t stream)
{
    const float* x   = (const float*)d_in[0];
    const float* ctx = (const float*)d_in[1];
    const float* W0  = (const float*)d_in[2];
    const float* b0  = (const float*)d_in[3];
    const float* Wc  = (const float*)d_in[4];
    const float* bc  = (const float*)d_in[5];
    const float* Wr  = (const float*)d_in[6];
    const float* br  = (const float*)d_in[7];
    const float* Wf  = (const float*)d_in[8];
    const float* bfb = (const float*)d_in[9];
    int B = in_sizes[0] / 16;

    f16_t* wp  = (f16_t*)d_ws;                     // 12.78 MB packed f16 weights
    f16_t* c16 = (f16_t*)((char*)d_ws + CTX_BYTE); // 33.5 MB f16 context (optional)
    bool useCtx16 = ws_size >= CTX_BYTE + (size_t)B * CDIM * 2;

    nsf_pack<<<(PACK_TOTAL + 255) / 256, 256, 0, stream>>>(W0, Wc, Wr, Wf, wp);
    if (useCtx16) {
        int n4 = B * CDIM / 4;
        nsf_ctx16<<<(n4 + 255) / 256, 256, 0, stream>>>(ctx, c16, n4);
        nsf_flow<true><<<B / BROWS, 256, 0, stream>>>(x, ctx, c16, b0, bc, br, bfb, wp, (float*)d_out, B);
    } else {
        nsf_flow<false><<<B / BROWS, 256, 0, stream>>>(x, ctx, c16, b0, bc, br, bfb, wp, (float*)d_out, B);
    }
}

// Round 8
// 1905.722 us; speedup vs baseline: 1.5734x; 1.5734x over previous
//
#include <hip/hip_runtime.h>

typedef _Float16 f16_t;
typedef _Float16 f16x8 __attribute__((ext_vector_type(8)));
typedef _Float16 f16x4 __attribute__((ext_vector_type(4)));
typedef _Float16 f16x2 __attribute__((ext_vector_type(2)));
typedef float    f32x4 __attribute__((ext_vector_type(4)));

#define LAYERS 12
#define HDIM   256
#define CDIM   256
#define BROWS  32     // batch rows per block

// packed-weight workspace layout (f16 elements)
#define W0P_OFF 0
#define WCP_OFF 8192
#define WRP_OFF 73728
#define WRP_SZ  65536
#define WFP_OFF 335872
#define LSTRIDE 532480
#define PACK_TOTAL (LAYERS * LSTRIDE)
#define CTX_BYTE ((size_t)PACK_TOTAL * 2)

// s_waitcnt immediates (gfx9 encoding: vm[3:0], exp[6:4], lgkm[11:8], vm_hi[15:14])
#define WAIT_VM(N)  __builtin_amdgcn_s_waitcnt(0x0F70 | (N))   // vmcnt<=N, others free
#define WAIT_LGKM0  __builtin_amdgcn_s_waitcnt(0xC07F)         // lgkmcnt==0, others free

// ---------------------------------------------------------------------------
// Prepass: mask + cast + pack weights into MFMA B-fragment order.
// B-frag for 16x16x32: element (n = lane&15, k = quad*8+j) of tile (nt,kt)
// stored at ((nt*KT + kt)*64 + lane)*8 + j  -> one 16B chunk per lane,
// wave-contiguous: exactly the global_load_lds (uniform base + lane*16) shape.
// ---------------------------------------------------------------------------
__global__ __launch_bounds__(256) void nsf_pack(
    const float* __restrict__ W0, const float* __restrict__ Wc,
    const float* __restrict__ Wr, const float* __restrict__ Wf,
    f16_t* __restrict__ wp)
{
    int e = blockIdx.x * 256 + threadIdx.x;
    if (e >= PACK_TOTAL) return;
    int l = e / LSTRIDE;
    int r = e - l * LSTRIDE;
    float v = 0.f;
    if (r < WCP_OFF) {                       // W0p: N=256, K=32 (padded from 16), masked m0
        int t = r >> 9, lane = (r >> 3) & 63, j = r & 7;
        int n = t * 16 + (lane & 15);
        int k = (lane >> 4) * 8 + j;
        if (k < 16 && (n % 15 + 1) >= (k + 1))
            v = W0[(l * HDIM + n) * 16 + k];
    } else if (r < WRP_OFF) {                // Wcp: N=256, K=256, no mask
        int q = r - WCP_OFF;
        int t = q >> 9, lane = (q >> 3) & 63, j = q & 7;
        int n = (t >> 3) * 16 + (lane & 15);
        int k = (t & 7) * 32 + (lane >> 4) * 8 + j;
        v = Wc[(l * HDIM + n) * CDIM + k];
    } else if (r < WFP_OFF) {                // Wrp[4]: N=256, K=256, masked mh
        int q = r - WRP_OFF;
        int rr = q >> 16; q &= 65535;
        int t = q >> 9, lane = (q >> 3) & 63, j = q & 7;
        int n = (t >> 3) * 16 + (lane & 15);
        int k = (t & 7) * 32 + (lane >> 4) * 8 + j;
        if ((n % 15) >= (k % 15))
            v = Wr[(((l * 2 + (rr >> 1)) * 2 + (rr & 1)) * HDIM + n) * HDIM + k];
    } else {                                 // Wfp: N=768 (16 feats x 48, padded from 47), masked mf
        int q = r - WFP_OFF;
        int t = q >> 9, lane = (q >> 3) & 63, j = q & 7;
        int np = (t >> 3) * 16 + (lane & 15);
        int k = (t & 7) * 32 + (lane >> 4) * 8 + j;
        int f = np / 48, jj = np % 48;
        if (jj < 47 && (f + 1) > (k % 15 + 1))
            v = Wf[(l * 752 + f * 47 + jj) * HDIM + k];
    }
    wp[e] = (f16_t)v;
}

__global__ __launch_bounds__(256) void nsf_ctx16(
    const float* __restrict__ ctx, f16_t* __restrict__ c16, int n4)
{
    int i = blockIdx.x * 256 + threadIdx.x;
    if (i >= n4) return;
    float4 v = reinterpret_cast<const float4*>(ctx)[i];
    f16x4 o = { (f16_t)v.x, (f16_t)v.y, (f16_t)v.z, (f16_t)v.w };
    reinterpret_cast<f16x4*>(c16)[i] = o;
}

// ---------------------------------------------------------------------------
__device__ __forceinline__ float splus(float x) {   // softplus, fast HW ops only
    return fmaxf(x, 0.f) + __logf(1.f + __expf(-fabsf(x)));
}
__device__ __forceinline__ float loF(unsigned u) {
    f16x2 h = __builtin_bit_cast(f16x2, u); return (float)h[0];
}
__device__ __forceinline__ float hiF(unsigned u) {
    f16x2 h = __builtin_bit_cast(f16x2, u); return (float)h[1];
}

// async 16B/lane global->LDS (dst = uniform base + lane*16), zero VGPR data regs
__device__ __forceinline__ void load_lds16(const f16_t* g, f16_t* l) {
    __builtin_amdgcn_global_load_lds(
        (const __attribute__((address_space(1))) void*)(g),
        (__attribute__((address_space(3))) void*)(l), 16, 0, 0);
}

// issue one kt-slice (4 n-tiles) of B-weights into this wave's LDS slot
__device__ __forceinline__ void issue4(const f16_t* gbase, f16_t* slot, int kt) {
#pragma unroll
    for (int ni = 0; ni < 4; ++ni)
        load_lds16(gbase + ni * 4096 + kt * 512, slot + ni * 512);
}
__device__ __forceinline__ void issue3(const f16_t* gbase, f16_t* slot, int kt) {
#pragma unroll
    for (int ni = 0; ni < 3; ++ni)
        load_lds16(gbase + ni * 4096 + kt * 512, slot + ni * 512);
}

// C = A(32x256, LDS) * W^T(256x256), W streamed via global_load_lds, 2-deep
__device__ __forceinline__ void gemm256_lds(f32x4 (&acc)[2][4],
                                            const f16_t (&A)[BROWS][264],
                                            const f16_t* __restrict__ wb,
                                            f16_t* s0, f16_t* s1,
                                            int wave, int lane, int quad, int l16)
{
    const f16_t* gbase = wb + (size_t)wave * 4 * 4096 + lane * 8;  // + ni*4096 + kt*512
    issue4(gbase, s0, 0);
    issue4(gbase, s1, 1);
#pragma unroll
    for (int kt = 0; kt < 8; ++kt) {
        f16_t* cs = (kt & 1) ? s1 : s0;
        if (kt < 7) WAIT_VM(4); else WAIT_VM(0);
        f16x8 b[4];
#pragma unroll
        for (int ni = 0; ni < 4; ++ni)
            b[ni] = *reinterpret_cast<const f16x8*>(cs + ni * 512 + lane * 8);
        f16x8 a[2];
#pragma unroll
        for (int mi = 0; mi < 2; ++mi)
            a[mi] = *reinterpret_cast<const f16x8*>(&A[mi * 16 + l16][kt * 32 + quad * 8]);
#pragma unroll
        for (int ni = 0; ni < 4; ++ni)
#pragma unroll
            for (int mi = 0; mi < 2; ++mi)
                acc[mi][ni] = __builtin_amdgcn_mfma_f32_16x16x32_f16(a[mi], b[ni], acc[mi][ni], 0, 0, 0);
        if (kt < 6) { WAIT_LGKM0; issue4(gbase, cs, kt + 2); }
    }
}

template <bool RELU>
__device__ __forceinline__ void stage_c(const f32x4 (&acc)[2][4], f16_t (&A)[BROWS][264],
                                        int wave, int quad, int l16)
{
#pragma unroll
    for (int mi = 0; mi < 2; ++mi)
#pragma unroll
        for (int ni = 0; ni < 4; ++ni)
#pragma unroll
            for (int rr = 0; rr < 4; ++rr) {
                float v = acc[mi][ni][rr];
                if (RELU) v = fmaxf(v, 0.f);
                A[mi * 16 + quad * 4 + rr][wave * 64 + ni * 16 + l16] = (f16_t)v;
            }
}

// ---------------------------------------------------------------------------
// Persistent flow kernel, 32 batch rows/block. 2 blocks/CU (LDS 66 KB),
// 2 waves/SIMD -> 256 unified regs/wave: no spills, deep pipelines.
// Weights stream through per-wave LDS slots (global_load_lds, vmcnt-pipelined,
// barrier-free). Gf+spline are fully wave-local (feature f = wave*4+chunk).
// ---------------------------------------------------------------------------
template <bool CTX16>
__global__ __launch_bounds__(256, 2)
void nsf_flow(
    const float* __restrict__ x_in, const float* __restrict__ ctx32,
    const f16_t* __restrict__ ctx16,
    const float* __restrict__ b0, const float* __restrict__ bc,
    const float* __restrict__ br, const float* __restrict__ bfb,
    const f16_t* __restrict__ wp,
    float* __restrict__ out, int B)
{
    __shared__ f16_t act[BROWS][264];          // 16896 B  A-operand (activations)
    __shared__ __align__(16) f16_t wbuf[4][2][2048]; // 32768 B  per-wave weight slots
    __shared__ f16_t pldsw[4][32][50];         // 12800 B  per-wave spline params
    __shared__ f16_t xstage[BROWS][40];        //  2560 B  flipped-x A tile
    __shared__ float xbuf[BROWS][16];          //  2048 B  fp32 x state
    __shared__ float ldsum[32][4];             //   512 B  logdet partials

    const int tid  = threadIdx.x;
    const int wave = tid >> 6, lane = tid & 63;
    const int quad = lane >> 4, l16 = lane & 15;
    const int row0 = blockIdx.x * BROWS;

    f16_t* s0 = &wbuf[wave][0][0];
    f16_t* s1 = &wbuf[wave][1][0];

    for (int i = tid; i < BROWS * 16; i += 256)
        xbuf[i >> 4][i & 15] = x_in[(size_t)row0 * 16 + i];

    float ld_acc = 0.f;

#pragma unroll 1
    for (int l = 0; l < LAYERS; ++l) {
        const f16_t* wl = wp + (size_t)l * LSTRIDE;
        __syncthreads();   // prior layer fully consumed act/xbuf (incl. all splines)

        // spline inputs for this wave's features f=wave*4+c, row=lane (lanes<32)
        float xval_c[4];
        if (lane < 32) {
#pragma unroll
            for (int c = 0; c < 4; ++c) xval_c[c] = xbuf[lane][15 - (wave * 4 + c)];
        }

        // stage ctx -> act (f16)
        if (CTX16) {
#pragma unroll
            for (int it = 0; it < 4; ++it) {
                int j = it * 256 + tid;          // 1024 chunks of 16B
                int rr = j >> 5, cg = j & 31;
                f16x8 v = *reinterpret_cast<const f16x8*>(ctx16 + (size_t)(row0 + rr) * CDIM + cg * 8);
                *reinterpret_cast<f16x8*>(&act[rr][cg * 8]) = v;
            }
        } else {
            int rr = tid >> 3, cg = tid & 7;
            const float* cptr = ctx32 + (size_t)(row0 + rr) * CDIM + cg * 32;
#pragma unroll
            for (int it = 0; it < 8; ++it) {
                float4 v = *reinterpret_cast<const float4*>(cptr + it * 4);
                f16x4 w4 = { (f16_t)v.x, (f16_t)v.y, (f16_t)v.z, (f16_t)v.w };
                *reinterpret_cast<f16x4*>(&act[rr][cg * 32 + it * 4]) = w4;
            }
        }
        // stage flipped x (zero-padded K 16..31) -> xstage
        for (int i = tid; i < BROWS * 32; i += 256) {
            int rr = i >> 5, c = i & 31;
            float v = (c < 16) ? xbuf[rr][15 - c] : 0.f;
            xstage[rr][c] = (f16_t)v;
        }
        __syncthreads();

        // ---- h = xf @ (W0*m0)^T + ctx @ Wc^T + b0 + bc ----
        f32x4 hacc[2][4];
#pragma unroll
        for (int ni = 0; ni < 4; ++ni) {
            int n = wave * 64 + ni * 16 + l16;
            float bv = b0[l * HDIM + n] + bc[l * HDIM + n];
#pragma unroll
            for (int mi = 0; mi < 2; ++mi) hacc[mi][ni] = (f32x4){bv, bv, bv, bv};
        }
        {
            f16x8 a[2];
#pragma unroll
            for (int mi = 0; mi < 2; ++mi)
                a[mi] = *reinterpret_cast<const f16x8*>(&xstage[mi * 16 + l16][quad * 8]);
#pragma unroll
            for (int ni = 0; ni < 4; ++ni) {
                f16x8 b = *reinterpret_cast<const f16x8*>(wl + W0P_OFF + ((wave * 4 + ni) * 64 + lane) * 8);
#pragma unroll
                for (int mi = 0; mi < 2; ++mi)
                    hacc[mi][ni] = __builtin_amdgcn_mfma_f32_16x16x32_f16(a[mi], b, hacc[mi][ni], 0, 0, 0);
            }
        }
        gemm256_lds(hacc, act, wl + WCP_OFF, s0, s1, wave, lane, quad, l16);

        // ---- 2 residual blocks ----
#pragma unroll 1
        for (int blk = 0; blk < 2; ++blk) {
            __syncthreads();
            stage_c<true>(hacc, act, wave, quad, l16);
            __syncthreads();
            f32x4 tacc[2][4];
#pragma unroll
            for (int ni = 0; ni < 4; ++ni) {
                int n = wave * 64 + ni * 16 + l16;
                float bv = br[((l * 2 + blk) * 2 + 0) * HDIM + n];
#pragma unroll
                for (int mi = 0; mi < 2; ++mi) tacc[mi][ni] = (f32x4){bv, bv, bv, bv};
            }
            gemm256_lds(tacc, act, wl + WRP_OFF + (size_t)(blk * 2) * WRP_SZ, s0, s1, wave, lane, quad, l16);
            __syncthreads();
            stage_c<true>(tacc, act, wave, quad, l16);
            __syncthreads();
#pragma unroll
            for (int ni = 0; ni < 4; ++ni) {
                int n = wave * 64 + ni * 16 + l16;
                float bv = br[((l * 2 + blk) * 2 + 1) * HDIM + n];
#pragma unroll
                for (int mi = 0; mi < 2; ++mi) tacc[mi][ni] = (f32x4){bv, bv, bv, bv};
            }
            gemm256_lds(tacc, act, wl + WRP_OFF + (size_t)(blk * 2 + 1) * WRP_SZ, s0, s1, wave, lane, quad, l16);
#pragma unroll
            for (int mi = 0; mi < 2; ++mi)
#pragma unroll
                for (int ni = 0; ni < 4; ++ni)
                    hacc[mi][ni] += tacc[mi][ni];
        }

        // ---- stage final h (no relu) ----
        __syncthreads();
        stage_c<false>(hacc, act, wave, quad, l16);
        __syncthreads();

        // ---- Gf + spline: fully wave-local, barrier-free ----
        // wave w, chunk c -> feature f = w*4+c, Wf tiles 3f..3f+2
#pragma unroll 1
        for (int c = 0; c < 4; ++c) {
            const int f = wave * 4 + c;
            const f16_t* gbase = wl + WFP_OFF + (size_t)(3 * f) * 4096 + lane * 8;
            f32x4 pacc[2][3];
#pragma unroll
            for (int ni = 0; ni < 3; ++ni) {
                int jj = ni * 16 + l16;
                float bv = (jj < 47) ? bfb[l * 752 + f * 47 + jj] : 0.f;
#pragma unroll
                for (int mi = 0; mi < 2; ++mi) pacc[mi][ni] = (f32x4){bv, bv, bv, bv};
            }
            issue3(gbase, s0, 0);
            issue3(gbase, s1, 1);
#pragma unroll
            for (int kt = 0; kt < 8; ++kt) {
                f16_t* cs = (kt & 1) ? s1 : s0;
                if (kt < 7) WAIT_VM(3); else WAIT_VM(0);
                f16x8 b[3];
#pragma unroll
                for (int ni = 0; ni < 3; ++ni)
                    b[ni] = *reinterpret_cast<const f16x8*>(cs + ni * 512 + lane * 8);
                f16x8 a[2];
#pragma unroll
                for (int mi = 0; mi < 2; ++mi)
                    a[mi] = *reinterpret_cast<const f16x8*>(&act[mi * 16 + l16][kt * 32 + quad * 8]);
#pragma unroll
                for (int ni = 0; ni < 3; ++ni)
#pragma unroll
                    for (int mi = 0; mi < 2; ++mi)
                        pacc[mi][ni] = __builtin_amdgcn_mfma_f32_16x16x32_f16(a[mi], b[ni], pacc[mi][ni], 0, 0, 0);
                if (kt < 6) { WAIT_LGKM0; issue3(gbase, cs, kt + 2); }
            }
            // park p in this wave's private LDS (row = batch, col = jj)
            WAIT_LGKM0;
#pragma unroll
            for (int mi = 0; mi < 2; ++mi)
#pragma unroll
                for (int ni = 0; ni < 3; ++ni)
#pragma unroll
                    for (int rr = 0; rr < 4; ++rr)
                        pldsw[wave][mi * 16 + quad * 4 + rr][ni * 16 + l16] = (f16_t)pacc[mi][ni][rr];
            WAIT_LGKM0;   // ds in-order per wave + drained: rows visible to all lanes

            // ---- RQ spline: lanes 0..31, row = lane, feature f ----
            if (lane < 32) {
                float xval = xval_c[c];
                const unsigned* pp = reinterpret_cast<const unsigned*>(&pldsw[wave][lane][0]);
                float uw[16], uh[16], ud[15];
#pragma unroll
                for (int j = 0; j < 8; ++j) {
                    unsigned w2 = pp[j], h2 = pp[8 + j];
                    uw[2 * j]     = loF(w2) * 0.0625f;
                    uw[2 * j + 1] = hiF(w2) * 0.0625f;
                    uh[2 * j]     = loF(h2) * 0.0625f;
                    uh[2 * j + 1] = hiF(h2) * 0.0625f;
                }
#pragma unroll
                for (int j = 0; j < 7; ++j) {
                    unsigned d2 = pp[16 + j];
                    ud[2 * j]     = loF(d2);
                    ud[2 * j + 1] = hiF(d2);
                }
                ud[14] = loF(pp[23]);

                float mw = uw[0], mh2 = uh[0];
#pragma unroll
                for (int j = 1; j < 16; ++j) { mw = fmaxf(mw, uw[j]); mh2 = fmaxf(mh2, uh[j]); }
                float sw = 0.f, sh = 0.f;
#pragma unroll
                for (int j = 0; j < 16; ++j) {
                    uw[j] = __expf(uw[j] - mw); sw += uw[j];
                    uh[j] = __expf(uh[j] - mh2); sh += uh[j];
                }
                float rw = 0.984f / sw, rh = 0.984f / sh;
                float xc = fminf(fmaxf(xval, -3.f), 3.f);
                float cumw = 0.f, cumh = 0.f, dprev = 1.f;
                float icw = -3.f, iwv = 1.f, ich = -3.f, ihv = 1.f, dk = 1.f, dk1 = 1.f;
#pragma unroll
                for (int j = 0; j < 16; ++j) {
                    float wj = fmaf(rw, uw[j], 0.001f);
                    float hj = fmaf(rh, uh[j], 0.001f);
                    float cwn = cumw + wj, chn = cumh + hj;
                    float left  = (j == 0)  ? -3.f : fmaf(6.f, cumw, -3.f);
                    float right = (j == 15) ?  3.f : fmaf(6.f, cwn, -3.f);
                    float hl    = (j == 0)  ? -3.f : fmaf(6.f, cumh, -3.f);
                    float hr    = (j == 15) ?  3.f : fmaf(6.f, chn, -3.f);
                    float dn    = (j == 15) ? 1.f : (0.001f + splus(ud[j]));
                    if (xc >= left) {
                        icw = left; iwv = right - left;
                        ich = hl;   ihv = hr - hl;
                        dk = dprev; dk1 = dn;
                    }
                    cumw = cwn; cumh = chn; dprev = dn;
                }
                float delta = ihv / iwv;
                float th = (xc - icw) / iwv;
                float omth = 1.f - th;
                float t1m = th * omth;
                float den = delta + (dk + dk1 - 2.f * delta) * t1m;
                float y = ich + ihv * (delta * th * th + dk * t1m) / den;
                float dnum = delta * delta * (dk1 * th * th + 2.f * delta * t1m + dk * omth * omth);
                float ldv = __logf(dnum) - 2.f * __logf(den);
                bool inside = (xval >= -3.f) && (xval <= 3.f);
                xbuf[lane][f] = inside ? y : xval;
                ld_acc += inside ? ldv : 0.f;
            }
        }
    }

    __syncthreads();
    for (int i = tid; i < BROWS * 16; i += 256)
        out[(size_t)row0 * 16 + i] = xbuf[i >> 4][i & 15];
    if (lane < 32) ldsum[lane][wave] = ld_acc;
    __syncthreads();
    if (tid < 32)
        out[(size_t)B * 16 + row0 + tid] =
            ldsum[tid][0] + ldsum[tid][1] + ldsum[tid][2] + ldsum[tid][3];
}

// ---------------------------------------------------------------------------
extern "C" void kernel_launch(void* const* d_in, const int* in_sizes, int n_in,
                              void* d_out, int out_size, void* d_ws, size_t ws_size,
                              hipStream_t stream)
{
    const float* x   = (const float*)d_in[0];
    const float* ctx = (const float*)d_in[1];
    const float* W0  = (const float*)d_in[2];
    const float* b0  = (const float*)d_in[3];
    const float* Wc  = (const float*)d_in[4];
    const float* bc  = (const float*)d_in[5];
    const float* Wr  = (const float*)d_in[6];
    const float* br  = (const float*)d_in[7];
    const float* Wf  = (const float*)d_in[8];
    const float* bfb = (const float*)d_in[9];
    int B = in_sizes[0] / 16;

    f16_t* wp  = (f16_t*)d_ws;                     // 12.78 MB packed f16 weights
    f16_t* c16 = (f16_t*)((char*)d_ws + CTX_BYTE); // 33.5 MB f16 context (optional)
    bool useCtx16 = ws_size >= CTX_BYTE + (size_t)B * CDIM * 2;

    nsf_pack<<<(PACK_TOTAL + 255) / 256, 256, 0, stream>>>(W0, Wc, Wr, Wf, wp);
    if (useCtx16) {
        int n4 = B * CDIM / 4;
        nsf_ctx16<<<(n4 + 255) / 256, 256, 0, stream>>>(ctx, c16, n4);
        nsf_flow<true><<<B / BROWS, 256, 0, stream>>>(x, ctx, c16, b0, bc, br, bfb, wp, (float*)d_out, B);
    } else {
        nsf_flow<false><<<B / BROWS, 256, 0, stream>>>(x, ctx, c16, b0, bc, br, bfb, wp, (float*)d_out, B);
    }
}